// Round 4
// baseline (409.296 us; speedup 1.0000x reference)
//
#include <hip/hip_runtime.h>
#include <hip/hip_bf16.h>
#include <stdint.h>

// out[2048,256] = x[2048,32768] @ W[32768,256],
// W[k,r] = U0[k&31, r] * U1[(k>>5)&31, r] * U2[k>>10, r]
//
// R4: (1) wgen emits W directly in MFMA B-fragment order -> gemm reads B
//     fragments straight from global (L2-resident, no LDS, no async staging,
//     barrier only guards the 16 KB A tile). (2) split-K partials in bf16
//     (halved traffic). (3) no d_out memset (reduce writes every element).

#define K_DIM 32768
#define R_DIM 256
#define M_DIM 2048
#define BM 128
#define BN 256
#define BK 64
#define SK 32
#define KC (K_DIM / SK)   // 1024 K per block
#define NKI (KC / BK)     // 16 iterations
#define OUT_ELEMS (M_DIM * R_DIM)   // 524288

typedef float f32x4 __attribute__((ext_vector_type(4)));
typedef short s16x8 __attribute__((ext_vector_type(8)));

// pack two fp32 -> two bf16 (round via +0x8000, v_perm byte pick)
__device__ __forceinline__ uint32_t pack2_bf16(float a, float b) {
    uint32_t ua = __builtin_bit_cast(uint32_t, a) + 0x8000u;
    uint32_t ub = __builtin_bit_cast(uint32_t, b) + 0x8000u;
    return __builtin_amdgcn_perm(ub, ua, 0x07060302u);
}

__device__ __forceinline__ uint16_t to_bf16(float a) {
    return (uint16_t)((__builtin_bit_cast(uint32_t, a) + 0x8000u) >> 16);
}

// ---------------------------------------------------------------------------
// Kernel 1: Wf bf16 in MFMA B-fragment order.
//   halfword offset((t,ks,q,n)) = ((t*2+ks)*16 + (n>>4))*512 + q*128 + (n&15)*8
//   holds W[k = t*64 + ks*32 + q*8 .. +8][n].
// A wave's B fragment (fixed t,ks,ngroup) = 1 KB contiguous, lane l at l*16B.
// Thread = (t,ks,q,n), n fastest -> all U loads coalesced.
// ---------------------------------------------------------------------------
__global__ __launch_bounds__(256) void wgen_kernel(
        const float* __restrict__ U0, const float* __restrict__ U1,
        const float* __restrict__ U2, uint16_t* __restrict__ Wf) {
    uint32_t tid  = blockIdx.x * 256u + threadIdx.x;   // [0, 1<<20)
    uint32_t n    = tid & 255u;
    uint32_t rest = tid >> 8;
    uint32_t q    = rest & 3u;
    uint32_t ks   = (rest >> 2) & 1u;
    uint32_t t    = rest >> 3;                         // [0, 512)
    uint32_t i0   = q * 8u;                            // k0 & 31
    uint32_t i1   = (t * 2u + ks) & 31u;               // (k0>>5) & 31
    uint32_t i2   = t >> 4;                            // k0 >> 10
    float u12 = U1[i1 * 256u + n] * U2[i2 * 256u + n];
    float w[8];
#pragma unroll
    for (int e = 0; e < 8; ++e)
        w[e] = U0[(i0 + (uint32_t)e) * 256u + n] * u12;
    uint32_t q0 = pack2_bf16(w[0], w[1]);
    uint32_t q1 = pack2_bf16(w[2], w[3]);
    uint32_t q2 = pack2_bf16(w[4], w[5]);
    uint32_t q3 = pack2_bf16(w[6], w[7]);
    size_t off = (size_t)(((t * 2u + ks) * 16u + (n >> 4)) * 512u +
                          q * 128u + (n & 15u) * 8u);
    *(uint4*)(Wf + off) = make_uint4(q0, q1, q2, q3);
}

// ---------------------------------------------------------------------------
// Kernel 2: GEMM. 512 threads = 8 waves, 2(m) x 4(n) over 128x256 tile;
// wave tile 64x64 = 4x4 grid of 16x16x32 bf16 MFMA (acc 64 VGPR/thread).
// A: fp32 global -> bf16 in-register -> swizzled LDS (16 KB). B: fragment
// loads straight from global (L2-resident; bid%8==sk%8 pins same-sk blocks
// to one XCD). Grid 16 mblk x 32 sk = 512 blocks, 2 blocks/CU.
// Partials -> bf16 plain stores.
// ---------------------------------------------------------------------------
__global__ __launch_bounds__(512, 4) void gemm_kernel(
        const float* __restrict__ x, const uint16_t* __restrict__ Wf,
        uint16_t* __restrict__ part) {
    __shared__ uint16_t As[BM * 64];   // 16 KB

    const uint32_t bid  = blockIdx.x;
    const uint32_t sk   = bid & 31u;
    const uint32_t mblk = bid >> 5;

    const uint32_t tid  = threadIdx.x;
    const uint32_t lane = tid & 63u;
    const uint32_t wave = tid >> 6;          // [0,8)

    // ---- A staging: rows arow, arow+64; fp32 -> bf16; swizzled write
    const uint32_t ac   = tid & 7u;          // k-chunk (8 floats)
    const uint32_t arow = tid >> 3;          // [0,64)
    const uint32_t aswz = (ac ^ (arow & 7u)) * 8u;
    const float* xg = x + (size_t)(mblk * BM + arow) * K_DIM + sk * KC + ac * 8u;

    // ---- fragment addressing
    const uint32_t mloc = lane & 15u;
    const uint32_t quad = lane >> 4;
    const uint32_t wm = wave >> 2, wn = wave & 3u;
    const uint32_t sw0 = ((quad) ^ (mloc & 7u)) * 8u;        // ks=0
    const uint32_t sw1 = ((4u + quad) ^ (mloc & 7u)) * 8u;   // ks=1
    const uint32_t aRow0 = (wm * 64u + mloc) * 64u;

    // B fragment pointer: lane-constant part
    const uint16_t* pB = Wf + (size_t)(sk * NKI) * 16384u +
                         (wn * 4u) * 512u + quad * 128u + mloc * 8u;

    f32x4 acc[4][4];
#pragma unroll
    for (int i = 0; i < 4; ++i)
#pragma unroll
        for (int j = 0; j < 4; ++j) acc[i][j] = (f32x4){0.f, 0.f, 0.f, 0.f};

    for (uint32_t it = 0; it < NKI; ++it) {
        // A: 2 rows x 8 floats; convert; swizzled ds_write_b128
#pragma unroll
        for (int j = 0; j < 2; ++j) {
            const float* g = xg + (size_t)(j * 64) * K_DIM + it * BK;
            f32x4 v0 = *(const f32x4*)(g);
            f32x4 v1 = *(const f32x4*)(g + 4);
            uint32_t q0 = pack2_bf16(v0[0], v0[1]);
            uint32_t q1 = pack2_bf16(v0[2], v0[3]);
            uint32_t q2 = pack2_bf16(v1[0], v1[1]);
            uint32_t q3 = pack2_bf16(v1[2], v1[3]);
            *(uint4*)(&As[(arow + (uint32_t)j * 64u) * 64u + aswz]) =
                make_uint4(q0, q1, q2, q3);
        }
        __syncthreads();

        const uint16_t* pBt = pB + (size_t)it * 16384u;
#pragma unroll
        for (int ks = 0; ks < 2; ++ks) {
            const uint32_t sw = ks ? sw1 : sw0;
            s16x8 af[4], bf[4];
#pragma unroll
            for (int t = 0; t < 4; ++t)
                af[t] = *(const s16x8*)(&As[aRow0 + (uint32_t)t * 1024u + sw]);
#pragma unroll
            for (int nt = 0; nt < 4; ++nt)
                bf[nt] = *(const s16x8*)(pBt + ks * 8192u + (uint32_t)nt * 512u);
#pragma unroll
            for (int mt = 0; mt < 4; ++mt)
#pragma unroll
                for (int nt = 0; nt < 4; ++nt)
                    acc[mt][nt] = __builtin_amdgcn_mfma_f32_16x16x32_bf16(
                        af[mt], bf[nt], acc[mt][nt], 0, 0, 0);
        }
        __syncthreads();
    }

    // epilogue: bf16 partial stores
    uint16_t* po_base = part + (size_t)sk * OUT_ELEMS;
    const uint32_t orow0 = mblk * BM + wm * 64u + quad * 4u;
    const uint32_t ocol0 = wn * 64u + mloc;
#pragma unroll
    for (int mt = 0; mt < 4; ++mt) {
#pragma unroll
        for (int nt = 0; nt < 4; ++nt) {
            uint16_t* po = po_base +
                (size_t)(orow0 + (uint32_t)mt * 16u) * R_DIM +
                ocol0 + (uint32_t)nt * 16u;
#pragma unroll
            for (int i = 0; i < 4; ++i)
                po[(size_t)i * R_DIM] = to_bf16(acc[mt][nt][i]);
        }
    }
}

// ---------------------------------------------------------------------------
// Kernel 3: out[i] = sum_sk part[sk][i]; 8 outputs per thread (uint4 = 8 bf16)
// ---------------------------------------------------------------------------
__global__ __launch_bounds__(256) void reduce_kernel(
        const uint16_t* __restrict__ part, float* __restrict__ out) {
    uint32_t base = (blockIdx.x * 256u + threadIdx.x) * 8u;
    float s[8];
#pragma unroll
    for (int j = 0; j < 8; ++j) s[j] = 0.f;
    for (uint32_t skk = 0; skk < SK; ++skk) {
        uint4 v = *(const uint4*)(part + (size_t)skk * OUT_ELEMS + base);
        uint32_t w[4] = {v.x, v.y, v.z, v.w};
#pragma unroll
        for (int j = 0; j < 4; ++j) {
            s[2 * j]     += __builtin_bit_cast(float, w[j] << 16);
            s[2 * j + 1] += __builtin_bit_cast(float, w[j] & 0xffff0000u);
        }
    }
    f32x4 o0 = (f32x4){s[0], s[1], s[2], s[3]};
    f32x4 o1 = (f32x4){s[4], s[5], s[6], s[7]};
    *(f32x4*)(out + base) = o0;
    *(f32x4*)(out + base + 4) = o1;
}

extern "C" void kernel_launch(void* const* d_in, const int* in_sizes, int n_in,
                              void* d_out, int out_size, void* d_ws, size_t ws_size,
                              hipStream_t stream) {
    const float* x  = (const float*)d_in[0];
    const float* U0 = (const float*)d_in[1];
    const float* U1 = (const float*)d_in[2];
    const float* U2 = (const float*)d_in[3];
    float* out = (float*)d_out;

    uint16_t* Wf = (uint16_t*)d_ws;                            // 16 MiB
    uint16_t* part = (uint16_t*)((char*)d_ws + (32u << 20));   // 32 MiB bf16

    wgen_kernel<<<4096, 256, 0, stream>>>(U0, U1, U2, Wf);
    gemm_kernel<<<512, 512, 0, stream>>>(x, Wf, part);
    reduce_kernel<<<OUT_ELEMS / 8 / 256, 256, 0, stream>>>(part, out);
}